// Round 6
// baseline (216.945 us; speedup 1.0000x reference)
//
#include <hip/hip_runtime.h>

// GraphNodeEdgeConvolution: N=2048, K=8, FN=16, O=32. fp32 in / fp32 out.
// R6: fuse reduce+epilogue (one fewer launch). E-stream main_k is already at
// the coalesced-read roofline (134MB once, ~24us @ 6.3TB/s). Remaining gap
// to dur_us attributed to harness poison/restore dispatches (~180us floor):
// 512MB ws fill @ ~80us + d_in restores observed in rocprof on-stream.
constexpr int CN  = 2048;
constexpr int CK  = 8;
constexpr int CFN = 16;
constexpr int CO  = 32;

constexpr int JTILE  = 256;
constexpr int NJT    = CN / JTILE;     // 8
constexpr int CHUNK  = 32;
constexpr int NCHUNK = CN / CHUNK;     // 64 -> grid 8x64 = 512 blocks
constexpr int NACC   = CK + 1;         // 8 agg planes + 1 colsum plane

// Kernel 1: rinv[i] = 1/sum_j adj[i,j] (0 if non-finite)
__global__ __launch_bounds__(256) void rowsum_k(const float* __restrict__ adj,
                                                float* __restrict__ rinv) {
    const int i = blockIdx.x;
    const int t = threadIdx.x;
    const float4* row = (const float4*)(adj + (size_t)i * CN);  // 512 float4
    float4 v0 = row[t], v1 = row[t + 256];
    float s = v0.x + v0.y + v0.z + v0.w + v1.x + v1.y + v1.z + v1.w;
    #pragma unroll
    for (int off = 32; off > 0; off >>= 1) s += __shfl_down(s, off, 64);
    __shared__ float partial[4];
    if ((t & 63) == 0) partial[t >> 6] = s;
    __syncthreads();
    if (t == 0) {
        float tot = partial[0] + partial[1] + partial[2] + partial[3];
        float r = 1.0f / tot;
        if (!isfinite(r)) r = 0.0f;
        rinv[i] = r;
    }
}

// Kernel 2: stream E once; per-thread j-column accumulators over a 32-row
// i-chunk; store partials plane-major part[k][ic][j] (coalesced, no atomics).
__global__ __launch_bounds__(256) void main_k(const float* __restrict__ E,
                                              const float* __restrict__ adj,
                                              const float* __restrict__ rinv,
                                              float* __restrict__ part) {
    const int t  = threadIdx.x;
    const int j  = blockIdx.x * JTILE + t;
    const int ic = blockIdx.y;
    const int i0 = ic * CHUNK;

    float acc[NACC];
    #pragma unroll
    for (int k = 0; k < NACC; ++k) acc[k] = 0.f;

    #pragma unroll 4
    for (int ii = 0; ii < CHUNK; ++ii) {
        const int i = i0 + ii;
        const float a = rinv[i] * adj[(size_t)i * CN + j];
        const float4* ev = (const float4*)(E + ((size_t)i * CN + j) * CK); // 32B/lane
        const float4 e0 = ev[0];
        const float4 e1 = ev[1];
        acc[0] += a * e0.x; acc[1] += a * e0.y;
        acc[2] += a * e0.z; acc[3] += a * e0.w;
        acc[4] += a * e1.x; acc[5] += a * e1.y;
        acc[6] += a * e1.z; acc[7] += a * e1.w;
        acc[8] += a;
    }

    #pragma unroll
    for (int k = 0; k < NACC; ++k)
        part[(size_t)k * (NCHUNK * CN) + (size_t)ic * CN + j] = acc[k];
}

// Kernel 3 (fused reduce + epilogue): block b owns 32 j's.
// Stage 1: reduce part[k][*][j] over 64 chunks -> LDS[9][32].
// Stage 2: out[j,o] = sum_k agg[k][j]*W[k,o] + col[j]*sum_f NF[j,f]*W[8+f,o]
__global__ __launch_bounds__(256) void tail_k(const float* __restrict__ part,
                                              const float* __restrict__ nf,
                                              const float* __restrict__ wt,
                                              float* __restrict__ out) {
    const int t  = threadIdx.x;
    const int j0 = blockIdx.x * 32;

    __shared__ float red[NACC][32];   // 9 x 32 floats

    // Stage 1: 288 (k,j) pairs, each a 64-way sum. Threads loop p = t, t+256.
    for (int p = t; p < NACC * 32; p += 256) {
        const int k  = p >> 5;
        const int jj = p & 31;
        const float* q = part + (size_t)k * (NCHUNK * CN) + (j0 + jj);
        float s = 0.f;
        #pragma unroll 8
        for (int ic = 0; ic < NCHUNK; ++ic) s += q[(size_t)ic * CN];
        red[k][jj] = s;
    }
    __syncthreads();

    // Stage 2: 32 j x 32 o = 1024 outputs; each thread does 4.
    const int o = t & 31;
    #pragma unroll
    for (int r = 0; r < 4; ++r) {
        const int jj = (t >> 5) + r * 8;
        const int j  = j0 + jj;
        float s1 = 0.f;
        #pragma unroll
        for (int k = 0; k < CK; ++k)
            s1 += red[k][jj] * wt[k * CO + o];
        float s2 = 0.f;
        #pragma unroll
        for (int f = 0; f < CFN; ++f)
            s2 += nf[(size_t)j * CFN + f] * wt[(CK + f) * CO + o];
        out[(size_t)j * CO + o] = s1 + red[CK][jj] * s2;
    }
}

extern "C" void kernel_launch(void* const* d_in, const int* in_sizes, int n_in,
                              void* d_out, int out_size, void* d_ws, size_t ws_size,
                              hipStream_t stream) {
    // Bind inputs BY ELEMENT COUNT (all four counts distinct).
    const float *nf = nullptr, *E = nullptr, *adj = nullptr, *wt = nullptr;
    for (int i = 0; i < n_in; ++i) {
        switch (in_sizes[i]) {
            case CN * CFN:        nf  = (const float*)d_in[i]; break;  // 32768
            case CN * CN * CK:    E   = (const float*)d_in[i]; break;  // 33554432
            case CN * CN:         adj = (const float*)d_in[i]; break;  // 4194304
            case (CK + CFN) * CO: wt  = (const float*)d_in[i]; break;  // 768
        }
    }
    float* out = (float*)d_out;

    // ws (fp32): rinv[2048] | part[9*64*2048]; every ws word consumed is
    // written first by a prior kernel -> no memset needed.
    float* rinv = (float*)d_ws;
    float* part = rinv + CN;

    rowsum_k<<<CN, 256, 0, stream>>>(adj, rinv);
    main_k<<<dim3(NJT, NCHUNK), 256, 0, stream>>>(E, adj, rinv, part);
    tail_k<<<CN / 32, 256, 0, stream>>>(part, nf, wt, out);
}